// Round 1
// 263.573 us; speedup vs baseline: 1.0767x; 1.0767x over previous
//
#include <hip/hip_runtime.h>

// LieRE: out[n,y,x,q,:] = in[n,y,x,q,:] @ expm(y_v*S0 + x_v*S1)
// N=32,H=32,W=32,h=16,d=64. Transpose symmetry: rot[31-y][31-x] = rot[y][x]^T.
//
// Round 4: expm matmuls moved from fp32 VALU (LDS-read-bound, ~65us of the
// 131us) to bf16x3 split MFMA: each operand kept as (hi,lo) bf16 pair,
// products hh + hl + lh accumulated in fp32 (2^-18 relative per product).
// All matrices stay row-major. The MFMA D-layout writes the TRANSPOSED
// product contiguously, so one routine  dst = Q*P^T (+ c*I)  covers all:
//   Horner  newT = T*X + cI  : Q=T, P=-X  (X skew => -X = X^T); the fixed
//           -X A-fragments are hoisted into registers once for all 8 steps.
//   Squaring newS = S*S      : Q=S, P=S^T; S^T maintained by a cheap LDS
//           transpose pass per squaring (also provides RT for the apply).
// LDS: 6 slots of 64x72 bf16 (55.3 KB) -> still 2 blocks/CU.
// Phase 2 (apply) unchanged: barrier-free, R-fragments in registers,
// input streams global->reg(bf16)->MFMA->global.
// NOTE: batch (n) stride is H*W*h*d = 1<<20 floats.

typedef float f4 __attribute__((ext_vector_type(4)));
typedef short s8v __attribute__((ext_vector_type(8)));
typedef float f32x4 __attribute__((ext_vector_type(4)));
typedef unsigned short ush;
typedef unsigned int u32;
typedef ush us4 __attribute__((ext_vector_type(4)));

constexpr int LST = 68;          // fp32 staging stride (floats)
constexpr int BST = 72;          // bf16 row stride (ushorts); 144B rows, 16B-aligned
constexpr int SLOT = 64 * BST;   // one 64x64 bf16 matrix (ushorts)

static __device__ __forceinline__ ush f2bf(float f) {
    u32 u = __float_as_uint(f);
    u += 0x7fffu + ((u >> 16) & 1u);
    return (ush)(u >> 16);
}
static __device__ __forceinline__ float bf2f(ush h) {
    return __uint_as_float(((u32)h) << 16);
}
static __device__ __forceinline__ s8v negbf(s8v v) {
    u32* p = (u32*)&v;
#pragma unroll
    for (int i = 0; i < 4; ++i) p[i] ^= 0x80008000u;
    return v;
}

// Load this wave's 2x2x2 [tile][kslice][hi/lo] A/B fragments from a
// row-major bf16 (hi,lo) matrix. Rows base+t*16+m, k = ks*32 + q4*8 .. +7.
static __device__ __forceinline__ void load_frag(
    s8v fr[2][2][2], const ush* __restrict__ ah, const ush* __restrict__ al,
    int m, int q4, int base, bool neg)
{
#pragma unroll
    for (int t = 0; t < 2; ++t)
#pragma unroll
        for (int ks = 0; ks < 2; ++ks) {
            const int off = (base + t * 16 + m) * BST + ks * 32 + q4 * 8;
            s8v h = *(const s8v*)&ah[off];
            s8v l = *(const s8v*)&al[off];
            if (neg) { h = negbf(h); l = negbf(l); }
            fr[t][ks][0] = h;
            fr[t][ks][1] = l;
        }
}

// dst = Q * P^T + cdiag*I   (all row-major, bf16 hi/lo split, fp32 acc).
// pa = P's A-op fragments (rows DM..DM+31, pre-loaded; may be pre-negated).
// Q read from (qh,ql) rows DN..DN+31. Wave (DM,DN) writes dst rows
// DN..DN+31, cols DM..DM+31 (D^T contiguous store).
static __device__ __forceinline__ void mm_pre(
    ush* __restrict__ dh, ush* __restrict__ dl,
    const s8v pa[2][2][2],
    const ush* __restrict__ qh, const ush* __restrict__ ql,
    float cdiag, int m, int q4, int DM, int DN)
{
    s8v qb[2][2][2];
    load_frag(qb, qh, ql, m, q4, DN, false);

    f32x4 acc[2][2];
#pragma unroll
    for (int mt = 0; mt < 2; ++mt)
#pragma unroll
        for (int nt = 0; nt < 2; ++nt) acc[mt][nt] = (f32x4){0.f, 0.f, 0.f, 0.f};

#pragma unroll
    for (int ks = 0; ks < 2; ++ks)
#pragma unroll
        for (int mt = 0; mt < 2; ++mt)
#pragma unroll
            for (int nt = 0; nt < 2; ++nt) {
                acc[mt][nt] = __builtin_amdgcn_mfma_f32_16x16x32_bf16(
                    pa[mt][ks][0], qb[nt][ks][0], acc[mt][nt], 0, 0, 0);
                acc[mt][nt] = __builtin_amdgcn_mfma_f32_16x16x32_bf16(
                    pa[mt][ks][0], qb[nt][ks][1], acc[mt][nt], 0, 0, 0);
                acc[mt][nt] = __builtin_amdgcn_mfma_f32_16x16x32_bf16(
                    pa[mt][ks][1], qb[nt][ks][0], acc[mt][nt], 0, 0, 0);
            }

#pragma unroll
    for (int mt = 0; mt < 2; ++mt)
#pragma unroll
        for (int nt = 0; nt < 2; ++nt) {
            const int gm = DM + mt * 16 + q4 * 4;   // dst col base (4 regs)
            const int gn = DN + nt * 16 + m;        // dst row
            us4 h4, l4;
#pragma unroll
            for (int r = 0; r < 4; ++r) {
                float v = acc[mt][nt][r];
                if (gn == gm + r) v += cdiag;
                const ush h = f2bf(v);
                h4[r] = h;
                l4[r] = f2bf(v - bf2f(h));
            }
            *(us4*)&dh[gn * BST + gm] = h4;
            *(us4*)&dl[gn * BST + gm] = l4;
        }
}

// dst = src^T (both row-major bf16 hi/lo). Wave-conflict-friendly:
// r = tid&63 (per-lane row), k0 = 16-col stripe per wave.
static __device__ __forceinline__ void transp(
    ush* __restrict__ dh, ush* __restrict__ dl,
    const ush* __restrict__ sh, const ush* __restrict__ sl, int tid)
{
    const int r = tid & 63;
    const int k0 = (tid >> 6) << 4;
    s8v a0 = *(const s8v*)&sh[r * BST + k0];
    s8v a1 = *(const s8v*)&sh[r * BST + k0 + 8];
    s8v b0 = *(const s8v*)&sl[r * BST + k0];
    s8v b1 = *(const s8v*)&sl[r * BST + k0 + 8];
#pragma unroll
    for (int j = 0; j < 8; ++j) {
        dh[(k0 + j) * BST + r]     = ((const ush*)&a0)[j];
        dh[(k0 + j + 8) * BST + r] = ((const ush*)&a1)[j];
        dl[(k0 + j) * BST + r]     = ((const ush*)&b0)[j];
        dl[(k0 + j + 8) * BST + r] = ((const ush*)&b1)[j];
    }
}

__global__ __launch_bounds__(256, 2)
void liere_fused(const float* __restrict__ in, const float* __restrict__ emb,
                 float* __restrict__ out) {
    // Slot pairs: P0 = buf+0, P1 = buf+2*SLOT, P2 = buf+4*SLOT (hi,lo each).
    __shared__ __align__(16) ush buf[6 * SLOT];
    __shared__ float snorm;

    const int tid = threadIdx.x;
    const int p = blockIdx.x;          // 0..511
    const int y = p >> 5;              // 0..15
    const int x = p & 31;              // 0..31

    // fp32 staging aliases (each pair = 18432B >= 64*68*4 = 17408B)
    float* sG = (float*)(buf);              // gen scratch      (P0)
    float* sU = (float*)(buf + 2 * SLOT);   // emb[0] staging   (P1)
    float* sV = (float*)(buf + 4 * SLOT);   // emb[1] staging   (P2)

    // ---- stage emb[0] -> sU, emb[1] -> sV ----
#pragma unroll
    for (int i = 0; i < 4; ++i) {
        int lin = i * 1024 + tid * 4;
        int r = lin >> 6, c = lin & 63;
        *(f4*)&sU[r * LST + c] = *(const f4*)&emb[lin];
        *(f4*)&sV[r * LST + c] = *(const f4*)&emb[4096 + lin];
    }
    __syncthreads();

    // ---- build gen into sG ----
    const float yv = (2.0f * (float)y - 31.0f) / 31.0f;
    const float xv = (2.0f * (float)x - 31.0f) / 31.0f;
    {
        const int r0 = (tid >> 4) << 2, c0 = (tid & 15) << 2;
#pragma unroll
        for (int i = 0; i < 4; ++i)
#pragma unroll
            for (int j = 0; j < 4; ++j) {
                int r = r0 + i, c = c0 + j;
                float s0, s1;
                if (r < c)      { s0 = sU[r * LST + c];  s1 = sV[r * LST + c]; }
                else if (r > c) { s0 = -sU[c * LST + r]; s1 = -sV[c * LST + r]; }
                else            { s0 = 0.f; s1 = 0.f; }
                sG[r * LST + c] = yv * s0 + xv * s1;
            }
    }
    __syncthreads();

    // ---- 1-norm by wave 0 (row sums == col sums for skew) ----
    if (tid < 64) {
        float s = 0.f;
        for (int c = 0; c < 64; ++c) s += fabsf(sG[tid * LST + c]);
#pragma unroll
        for (int off = 32; off > 0; off >>= 1) s = fmaxf(s, __shfl_down(s, off, 64));
        if (tid == 0) snorm = s;
    }
    __syncthreads();
    int sq = 0;
    {
        float nm = snorm;
        if (nm > 1.0f) sq = (int)ceilf(log2f(nm));
        if (sq < 0) sq = 0;
        if (sq > 14) sq = 14;
    }
    const float scale = exp2f((float)(-sq));

    const float C9 = 2.75573192e-6f, C8 = 2.48015876e-5f, C7 = 1.98412701e-4f,
                C6 = 1.38888893e-3f, C5 = 8.33333377e-3f, C4 = 4.16666679e-2f,
                C3 = 0.166666672f,   C2 = 0.5f,           C1 = 1.0f, C0 = 1.0f;

    // bf16 hi/lo matrix slots
    ush* Xh = buf + 2 * SLOT;  ush* Xl = buf + 3 * SLOT;   // X      (P1, over sU)
    ush* t_h = buf + 4 * SLOT; ush* t_l = buf + 5 * SLOT;  // T ping (P2, over sV)
    ush* u_h = buf + 0 * SLOT; ush* u_l = buf + 1 * SLOT;  // T pong (P0, over sG)

    // ---- scale + split X (hi/lo) + init T0 = C9*X + C8*I ----
    {
        const int r0 = (tid >> 4) << 2, c0 = (tid & 15) << 2;
#pragma unroll
        for (int i = 0; i < 4; ++i)
#pragma unroll
            for (int j = 0; j < 4; ++j) {
                int r = r0 + i, c = c0 + j;
                float a = sG[r * LST + c] * scale;
                ush xh = f2bf(a);
                Xh[r * BST + c] = xh;
                Xl[r * BST + c] = f2bf(a - bf2f(xh));
                float t0 = C9 * a + ((r == c) ? C8 : 0.f);
                ush th = f2bf(t0);
                t_h[r * BST + c] = th;
                t_l[r * BST + c] = f2bf(t0 - bf2f(th));
            }
    }
    __syncthreads();

    const int lane = tid & 63;
    const int w = tid >> 6;
    const int m = lane & 15;
    const int q4 = lane >> 4;
    const int DM = (w & 1) * 32;   // dst cols / A-op rows
    const int DN = (w >> 1) * 32;  // dst rows / B-op rows

    // hoist P = -X (= X^T) A-fragments into registers for all Horner steps
    s8v xf[2][2][2];
    load_frag(xf, Xh, Xl, m, q4, DM, true);

    // ---- Horner: 8 MFMA matmuls, newT = T*X + c*I ----
    const float cs[8] = {C7, C6, C5, C4, C3, C2, C1, C0};
#pragma unroll
    for (int s = 0; s < 8; ++s) {
        mm_pre(u_h, u_l, xf, t_h, t_l, cs[s], m, q4, DM, DN);
        __syncthreads();
        ush* th2 = t_h; t_h = u_h; u_h = th2;
        ush* tl2 = t_l; t_l = u_l; u_l = tl2;
    }
    // t = T (P2), u = P0 free, X (P1) dead -> becomes T^T
    ush* tt_h = Xh; ush* tt_l = Xl;
    transp(tt_h, tt_l, t_h, t_l, tid);
    __syncthreads();

    // ---- squarings: newS = S*S (Q=S, P=S^T), then refresh S^T ----
    for (int i = 0; i < sq; ++i) {
        s8v af[2][2][2];
        load_frag(af, tt_h, tt_l, m, q4, DM, false);
        mm_pre(u_h, u_l, af, t_h, t_l, 0.f, m, q4, DM, DN);
        __syncthreads();
        transp(tt_h, tt_l, u_h, u_l, tid);
        __syncthreads();
        ush* th2 = t_h; t_h = u_h; u_h = th2;
        ush* tl2 = t_l; t_l = u_l; u_l = tl2;
    }
    // t_h = R row-major (hi = bf16(R)) == Rb ; tt_h = R^T row-major == RT

    // ---- apply: barrier-free, per-wave independent (unchanged) ----
    // out^T = A_op * B_op: A_op[m][k] = R[k][t*16+m] (pass0, from RT) or
    // R[t*16+m][k] (pass1, from Rb); B_op[k][n] = in[h=n][k].
    const int pass = w >> 1;           // waves 0,1 -> pass0; 2,3 -> pass1
    const int nbase = (w & 1) << 4;

    const ush* RF = pass ? t_h : tt_h;
    s8v rf[4][2];
#pragma unroll
    for (int t = 0; t < 4; ++t) {
        rf[t][0] = *(const s8v*)&RF[(t * 16 + m) * BST + q4 * 8];
        rf[t][1] = *(const s8v*)&RF[(t * 16 + m) * BST + 32 + q4 * 8];
    }

    const int yy = pass ? (31 - y) : y;
    const int xx = pass ? (31 - x) : x;
    const size_t pos = (size_t)(yy * 32 + xx) * 1024;

    for (int i = 0; i < 16; ++i) {
        const int n = nbase + i;
        const size_t nb = (size_t)n << 20;   // n stride = H*W*h*d = 1048576 floats
        const float* src = in + nb + pos + m * 64 + q4 * 8;
        f4 u0 = *(const f4*)src;
        f4 u1 = *(const f4*)(src + 4);
        f4 u2 = *(const f4*)(src + 32);
        f4 u3 = *(const f4*)(src + 36);
        s8v b0, b1;
        b0[0] = (short)f2bf(u0.x); b0[1] = (short)f2bf(u0.y);
        b0[2] = (short)f2bf(u0.z); b0[3] = (short)f2bf(u0.w);
        b0[4] = (short)f2bf(u1.x); b0[5] = (short)f2bf(u1.y);
        b0[6] = (short)f2bf(u1.z); b0[7] = (short)f2bf(u1.w);
        b1[0] = (short)f2bf(u2.x); b1[1] = (short)f2bf(u2.y);
        b1[2] = (short)f2bf(u2.z); b1[3] = (short)f2bf(u2.w);
        b1[4] = (short)f2bf(u3.x); b1[5] = (short)f2bf(u3.y);
        b1[6] = (short)f2bf(u3.z); b1[7] = (short)f2bf(u3.w);

        f32x4 acc0 = {0.f,0.f,0.f,0.f}, acc1 = acc0, acc2 = acc0, acc3 = acc0;
        acc0 = __builtin_amdgcn_mfma_f32_16x16x32_bf16(rf[0][0], b0, acc0, 0, 0, 0);
        acc0 = __builtin_amdgcn_mfma_f32_16x16x32_bf16(rf[0][1], b1, acc0, 0, 0, 0);
        acc1 = __builtin_amdgcn_mfma_f32_16x16x32_bf16(rf[1][0], b0, acc1, 0, 0, 0);
        acc1 = __builtin_amdgcn_mfma_f32_16x16x32_bf16(rf[1][1], b1, acc1, 0, 0, 0);
        acc2 = __builtin_amdgcn_mfma_f32_16x16x32_bf16(rf[2][0], b0, acc2, 0, 0, 0);
        acc2 = __builtin_amdgcn_mfma_f32_16x16x32_bf16(rf[2][1], b1, acc2, 0, 0, 0);
        acc3 = __builtin_amdgcn_mfma_f32_16x16x32_bf16(rf[3][0], b0, acc3, 0, 0, 0);
        acc3 = __builtin_amdgcn_mfma_f32_16x16x32_bf16(rf[3][1], b1, acc3, 0, 0, 0);

        float* dst = out + nb + pos + m * 64 + q4 * 4;
        f4 o0 = {acc0[0], acc0[1], acc0[2], acc0[3]};
        f4 o1 = {acc1[0], acc1[1], acc1[2], acc1[3]};
        f4 o2 = {acc2[0], acc2[1], acc2[2], acc2[3]};
        f4 o3 = {acc3[0], acc3[1], acc3[2], acc3[3]};
        *(f4*)(dst +  0) = o0;
        *(f4*)(dst + 16) = o1;
        *(f4*)(dst + 32) = o2;
        *(f4*)(dst + 48) = o3;
    }
}

extern "C" void kernel_launch(void* const* d_in, const int* in_sizes, int n_in,
                              void* d_out, int out_size, void* d_ws, size_t ws_size,
                              hipStream_t stream) {
    (void)in_sizes; (void)n_in; (void)out_size; (void)d_ws; (void)ws_size;
    const float* in = (const float*)d_in[0];
    const float* emb = (const float*)d_in[1];
    float* out = (float*)d_out;
    hipLaunchKernelGGL(liere_fused, dim3(512), dim3(256), 0, stream, in, emb, out);
}